// Round 5
// baseline (48.061 us; speedup 1.0000x reference)
//
#include <hip/hip_runtime.h>
#include <math.h>

// Stickbreaking attention (no mask):
//   att[i,t] = sigmoid(s[i,t]) * exp( sum_{j>=t} -softplus(s[i,j]) ),  s = QK^T/sqrt(D)
// Carry decays ~0.8/column => only top ~100 columns matter. Reverse-stream
// K-tiles, per-wave early exit when all 16 rows' carry < -40.
//
// v5: latency-hiding rework. v4 was latency-bound (VALUBusy 16%, VGPR=64 ->
// loads serialized one-at-a-time). Now: __launch_bounds__(64,2) for a 256-reg
// budget, double-buffered K-tile registers (prefetch next tile's 16 loads
// before current compute), V loads issued at tile start (hidden under
// QK-MFMA + scan). Math identical to v4 (passed, absmax 0.0078).

constexpr int B_ = 2, H_ = 16, S_ = 2048, D_ = 128;
constexpr int BK = 32, NTILES = S_ / BK;    // 64 tiles
constexpr int NJ = 256, NFT = NJ / BK;      // 8 precomputed "fast" tiles
constexpr float SCALE = 0.08838834764831845f;   // 1/sqrt(128)
constexpr float EXIT_THR = -40.0f;

typedef __attribute__((ext_vector_type(8))) short bf16x8;
typedef __attribute__((ext_vector_type(8))) _Float16 f16x8;
typedef __attribute__((ext_vector_type(8))) unsigned short u16x8;
typedef __attribute__((ext_vector_type(4))) float f32x4;
typedef __attribute__((ext_vector_type(2))) __fp16 fp16v2;

static __device__ __forceinline__ unsigned short bf16rtn(float x) {
    unsigned int u = __float_as_uint(x);
    u += 0x7FFFu + ((u >> 16) & 1u);
    return (unsigned short)(u >> 16);
}

// sigmoid(x) and log_sigmoid(-x) = -softplus(x), f32 (mirrors reference)
static __device__ __forceinline__ void zlb(float x, float& z, float& lb) {
    float en = __expf(-fabsf(x));
    float rc = __fdividef(1.0f, 1.0f + en);
    z  = (x >= 0.0f) ? rc : en * rc;
    lb = -(fmaxf(x, 0.0f) + __logf(1.0f + en));
}

// ---------------- pre-kernel: convert top-256 columns of K and V ----------------
__global__ __launch_bounds__(256)
void sb_pre(const float* __restrict__ kg, const float* __restrict__ vg,
            unsigned short* __restrict__ khi, unsigned short* __restrict__ klo,
            unsigned short* __restrict__ vt) {
    __shared__ float Vs[32][132];
    const int tid = threadIdx.x;
    const int blk = blockIdx.x;
    if (blk < 512) {
        size_t flat = ((size_t)blk * 256 + tid) * 8;
        int bh = (int)(flat / (NJ * D_));
        int rem = (int)(flat % (NJ * D_));
        int jj = rem / D_, d0 = rem % D_;
        const float* src = kg + ((size_t)bh * S_ + (S_ - NJ) + jj) * D_ + d0;
        u16x8 h8, l8;
        #pragma unroll
        for (int e = 0; e < 8; ++e) {
            float x = src[e];
            unsigned short hb = bf16rtn(x);
            float hf = __uint_as_float((unsigned int)hb << 16);
            h8[e] = hb;
            l8[e] = bf16rtn(x - hf);
        }
        size_t o = ((size_t)bh * NJ + jj) * D_ + d0;
        *(u16x8*)(khi + o) = h8;
        *(u16x8*)(klo + o) = l8;
    } else {
        int vb = blk - 512;
        int bh = vb >> 3, tt = vb & 7;
        const float* src = vg + ((size_t)bh * S_ + (S_ - NJ) + tt * 32) * D_;
        #pragma unroll
        for (int it = 0; it < 4; ++it) {
            int idx = it * 256 + tid;
            int j = idx >> 5, d4 = idx & 31;
            float4 val = *(const float4*)(src + (size_t)j * D_ + d4 * 4);
            *(float4*)&Vs[j][d4 * 4] = val;
        }
        __syncthreads();
        int d = tid >> 1, jh = (tid & 1) << 4;
        f16x8 v0, v1;
        #pragma unroll
        for (int j2 = 0; j2 < 8; ++j2) v0[j2] = (_Float16)Vs[jh + j2][d];
        #pragma unroll
        for (int j2 = 0; j2 < 8; ++j2) v1[j2] = (_Float16)Vs[jh + 8 + j2][d];
        unsigned short* dst = vt + (((size_t)bh * NFT + tt) * D_ + d) * 32 + jh;
        *(f16x8*)dst = v0;
        *(f16x8*)(dst + 8) = v1;
    }
}

// ---------------- K-tile register buffer ----------------
struct KTile {
    bf16x8 h0[4], l0[4], h1[4], l1[4];   // 64 VGPRs
};

static __device__ __forceinline__ void load_k_fast(
    KTile& kt, const unsigned short* __restrict__ khi,
    const unsigned short* __restrict__ klo, int bh, int tt, int m16, int g) {
    const size_t rb = ((size_t)bh * NJ + (size_t)(tt * 32 + m16)) * D_;
    const unsigned short* kr0h = khi + rb;
    const unsigned short* kr1h = kr0h + 16 * D_;
    const unsigned short* kr0l = klo + rb;
    const unsigned short* kr1l = kr0l + 16 * D_;
    #pragma unroll
    for (int ck = 0; ck < 4; ++ck) {
        const int off = ck * 32 + g * 8;
        kt.h0[ck] = *(const bf16x8*)(kr0h + off);
        kt.l0[ck] = *(const bf16x8*)(kr0l + off);
        kt.h1[ck] = *(const bf16x8*)(kr1h + off);
        kt.l1[ck] = *(const bf16x8*)(kr1l + off);
    }
}

// ---------------- scan + P pack + PV (shared by fast/slow) ----------------
static __device__ __forceinline__ float scan_pack_pv(
    f32x4 st0, f32x4 st1, int lane, int g, int m16,
    const f16x8* vf, f32x4* accO, unsigned int (*Pw)[20], float carry)
{
    float lbL[4], lbU[4], zL[4], zU[4];
    #pragma unroll
    for (int r = 0; r < 4; ++r) { zlb(st0[r], zL[r], lbL[r]); zlb(st1[r], zU[r], lbU[r]); }
    float sL3 = lbL[3], sL2 = lbL[2] + sL3, sL1 = lbL[1] + sL2, sL0 = lbL[0] + sL1;
    float sU3 = lbU[3], sU2 = lbU[2] + sU3, sU1 = lbU[1] + sU2, sU0 = lbU[0] + sU1;
    float sufL[4] = {sL0, sL1, sL2, sL3};
    float sufU[4] = {sU0, sU1, sU2, sU3};
    float TL = sL0, TU = sU0;
    float IU = TU, IL = TL;
    { float t1 = __shfl(IU, (lane + 16) & 63); if (g < 3) IU += t1;
      float t2 = __shfl(IU, (lane + 32) & 63); if (g < 2) IU += t2; }
    { float t1 = __shfl(IL, (lane + 16) & 63); if (g < 3) IL += t1;
      float t2 = __shfl(IL, (lane + 32) & 63); if (g < 2) IL += t2; }
    float TotU = __shfl(IU, m16);
    float EU = IU - TU, EL = IL - TL;
    float bU = carry + EU;
    float bL = carry + TotU + EL;
    float wU[4], wL[4];
    #pragma unroll
    for (int r = 0; r < 4; ++r) {
        wU[r] = zU[r] * __expf(bU + sufU[r]);
        wL[r] = zL[r] * __expf(bL + sufL[r]);
    }
    float TotL = __shfl(IL, m16);
    carry += TotU + TotL;

    union { fp16v2 h; unsigned int u; } cA, cB, cC, cD;
    cA.h = __builtin_amdgcn_cvt_pkrtz(wL[0], wL[1]);
    cB.h = __builtin_amdgcn_cvt_pkrtz(wL[2], wL[3]);
    cC.h = __builtin_amdgcn_cvt_pkrtz(wU[0], wU[1]);
    cD.h = __builtin_amdgcn_cvt_pkrtz(wU[2], wU[3]);
    *(uint2*)&Pw[m16][2 * g]     = make_uint2(cA.u, cB.u);
    *(uint2*)&Pw[m16][8 + 2 * g] = make_uint2(cC.u, cD.u);
    f16x8 pf = *(const f16x8*)&Pw[m16][4 * g];

    #pragma unroll
    for (int ck = 0; ck < 8; ++ck)
        accO[ck] = __builtin_amdgcn_mfma_f32_16x16x32_f16(pf, vf[ck], accO[ck], 0, 0, 0);
    return carry;
}

// ---------------- fast tile: V issue + QK from preloaded K regs ----------------
static __device__ __forceinline__ float fast_tile(
    int tt, int lane, int g, int m16, int bh,
    const unsigned short* __restrict__ vt, const KTile& kt,
    const bf16x8* qhi, const bf16x8* qlo,
    f32x4* accO, unsigned int (*Pw)[20], float carry)
{
    // V loads first — latency hides under QK MFMAs + scan
    f16x8 vf[8];
    #pragma unroll
    for (int ck = 0; ck < 8; ++ck)
        vf[ck] = *(const f16x8*)(vt + (((size_t)bh * NFT + tt) * D_ + ck * 16 + m16) * 32 + g * 8);

    f32x4 st0 = {0.f, 0.f, 0.f, 0.f}, st1 = {0.f, 0.f, 0.f, 0.f};
    #pragma unroll
    for (int ck = 0; ck < 4; ++ck) {
        st0 = __builtin_amdgcn_mfma_f32_16x16x32_bf16(kt.h0[ck], qhi[ck], st0, 0, 0, 0);
        st0 = __builtin_amdgcn_mfma_f32_16x16x32_bf16(kt.l0[ck], qhi[ck], st0, 0, 0, 0);
        st0 = __builtin_amdgcn_mfma_f32_16x16x32_bf16(kt.h0[ck], qlo[ck], st0, 0, 0, 0);
        st1 = __builtin_amdgcn_mfma_f32_16x16x32_bf16(kt.h1[ck], qhi[ck], st1, 0, 0, 0);
        st1 = __builtin_amdgcn_mfma_f32_16x16x32_bf16(kt.l1[ck], qhi[ck], st1, 0, 0, 0);
        st1 = __builtin_amdgcn_mfma_f32_16x16x32_bf16(kt.h1[ck], qlo[ck], st1, 0, 0, 0);
    }
    return scan_pack_pv(st0, st1, lane, g, m16, vf, accO, Pw, carry);
}

// ---------------- slow tile (cold; statistically never runs) ----------------
static __device__ __forceinline__ float slow_tile(
    int t, int lane, int g, int m16,
    const float* kb_p, const float* vb_p,
    const bf16x8* qhi, const bf16x8* qlo,
    f32x4* accO, unsigned int (*Pw)[20], float carry)
{
    const int j0 = t * BK;
    const float* kr0 = kb_p + (size_t)(j0 + m16) * D_;
    const float* kr1 = kr0 + (size_t)16 * D_;
    f32x4 st0 = {0.f, 0.f, 0.f, 0.f}, st1 = {0.f, 0.f, 0.f, 0.f};
    #pragma unroll
    for (int ck = 0; ck < 4; ++ck) {
        bf16x8 kh0, kl0, kh1, kl1;
        #pragma unroll
        for (int e = 0; e < 8; ++e) {
            float x0 = kr0[ck * 32 + g * 8 + e];
            unsigned short h0 = bf16rtn(x0);
            kh0[e] = (short)h0;
            kl0[e] = (short)bf16rtn(x0 - __uint_as_float((unsigned int)h0 << 16));
            float x1 = kr1[ck * 32 + g * 8 + e];
            unsigned short h1 = bf16rtn(x1);
            kh1[e] = (short)h1;
            kl1[e] = (short)bf16rtn(x1 - __uint_as_float((unsigned int)h1 << 16));
        }
        st0 = __builtin_amdgcn_mfma_f32_16x16x32_bf16(kh0, qhi[ck], st0, 0, 0, 0);
        st0 = __builtin_amdgcn_mfma_f32_16x16x32_bf16(kl0, qhi[ck], st0, 0, 0, 0);
        st0 = __builtin_amdgcn_mfma_f32_16x16x32_bf16(kh0, qlo[ck], st0, 0, 0, 0);
        st1 = __builtin_amdgcn_mfma_f32_16x16x32_bf16(kh1, qhi[ck], st1, 0, 0, 0);
        st1 = __builtin_amdgcn_mfma_f32_16x16x32_bf16(kl1, qhi[ck], st1, 0, 0, 0);
        st1 = __builtin_amdgcn_mfma_f32_16x16x32_bf16(kh1, qlo[ck], st1, 0, 0, 0);
    }
    f16x8 vf[8];
    #pragma unroll
    for (int ck = 0; ck < 8; ++ck) {
        #pragma unroll
        for (int e = 0; e < 8; ++e)
            vf[ck][e] = (_Float16)vb_p[(size_t)(j0 + g * 8 + e) * D_ + ck * 16 + m16];
    }
    return scan_pack_pv(st0, st1, lane, g, m16, vf, accO, Pw, carry);
}

// ---------------- main kernel: 1 wave per 16 query rows ----------------
template<int NFAST>
__global__ __launch_bounds__(64, 2)
void sb_attn(const float* __restrict__ qg, const float* __restrict__ kg,
             const float* __restrict__ vg, float* __restrict__ outg,
             const unsigned short* __restrict__ khi,
             const unsigned short* __restrict__ klo,
             const unsigned short* __restrict__ vt) {
    __shared__ unsigned int Pw[16][20];

    const int lane = threadIdx.x;
    const int g = lane >> 4, m16 = lane & 15;

    // XCD-chunked swizzle: same-head waves share an XCD L2
    const int bid = blockIdx.x;
    const int wg  = ((bid & 7) << 9) | (bid >> 3);
    const int bh  = wg >> 7;
    const int qb  = wg & 127;

    const float* qb_p = qg + ((size_t)bh * S_ + (size_t)qb * 16) * D_;
    const float* kb_p = kg + (size_t)bh * S_ * D_;
    const float* vb_p = vg + (size_t)bh * S_ * D_;
    float*       ob_p = outg + ((size_t)bh * S_ + (size_t)qb * 16) * D_;

    constexpr int TMIN = NTILES - NFAST;

    // issue first K tile's loads before the Q phase so both latencies overlap
    KTile ka, kb;
    if constexpr (NFAST > 0)
        load_k_fast(ka, khi, klo, bh, NTILES - 1 - TMIN, m16, g);

    // Q frags (persistent, bf16 hi/lo)
    bf16x8 qhi[4], qlo[4];
    #pragma unroll
    for (int ck = 0; ck < 4; ++ck) {
        const float* p = qb_p + (size_t)m16 * D_ + ck * 32 + g * 8;
        #pragma unroll
        for (int e = 0; e < 8; ++e) {
            float x = p[e] * SCALE;
            unsigned short hb = bf16rtn(x);
            float hf = __uint_as_float((unsigned int)hb << 16);
            qhi[ck][e] = (short)hb;
            qlo[ck][e] = (short)bf16rtn(x - hf);
        }
    }

    f32x4 accO[8];
    #pragma unroll
    for (int ck = 0; ck < 8; ++ck) accO[ck] = (f32x4){0.f, 0.f, 0.f, 0.f};

    float carry = 0.f;
    bool alive = true;
    int t = NTILES - 1;

    if constexpr (NFAST > 0) {
        while (true) {
            if (t - 1 >= TMIN) load_k_fast(kb, khi, klo, bh, t - 1 - TMIN, m16, g);
            carry = fast_tile(t - TMIN, lane, g, m16, bh, vt, ka, qhi, qlo, accO, Pw, carry);
            --t;
            if (__ballot(carry > EXIT_THR) == 0ULL) { alive = false; break; }
            if (t < TMIN) break;
            if (t - 1 >= TMIN) load_k_fast(ka, khi, klo, bh, t - 1 - TMIN, m16, g);
            carry = fast_tile(t - TMIN, lane, g, m16, bh, vt, kb, qhi, qlo, accO, Pw, carry);
            --t;
            if (__ballot(carry > EXIT_THR) == 0ULL) { alive = false; break; }
            if (t < TMIN) break;
        }
    }
    if (alive) {
        for (; t >= 0; --t) {
            carry = slow_tile(t, lane, g, m16, kb_p, vb_p, qhi, qlo, accO, Pw, carry);
            if (__ballot(carry > EXIT_THR) == 0ULL) break;
        }
    }

    // write O[4g+r][ck*16+m16]
    #pragma unroll
    for (int ck = 0; ck < 8; ++ck) {
        #pragma unroll
        for (int r = 0; r < 4; ++r) {
            ob_p[(size_t)(g * 4 + r) * D_ + ck * 16 + m16] = accO[ck][r];
        }
    }
}

extern "C" void kernel_launch(void* const* d_in, const int* in_sizes, int n_in,
                              void* d_out, int out_size, void* d_ws, size_t ws_size,
                              hipStream_t stream) {
    (void)in_sizes; (void)n_in; (void)out_size;
    const float* q = (const float*)d_in[0];
    const float* k = (const float*)d_in[1];
    const float* v = (const float*)d_in[2];
    float* out = (float*)d_out;

    const size_t kelems = (size_t)B_ * H_ * NJ * D_;
    const size_t need = 3 * kelems * 2;
    unsigned short* khi = (unsigned short*)d_ws;
    unsigned short* klo = khi + kelems;
    unsigned short* vt  = klo + kelems;

    dim3 grid(B_ * H_ * (S_ / 16));   // 4096 wave-blocks

    if (ws_size >= need) {
        sb_pre<<<768, 256, 0, stream>>>(k, v, khi, klo, vt);
        sb_attn<NFT><<<grid, 64, 0, stream>>>(q, k, v, out, khi, klo, vt);
    } else {
        sb_attn<0><<<grid, 64, 0, stream>>>(q, k, v, out, khi, klo, vt);
    }
}

// Round 6
// 44.129 us; speedup vs baseline: 1.0891x; 1.0891x over previous
//
#include <hip/hip_runtime.h>
#include <math.h>

// Stickbreaking attention (no mask):
//   att[i,t] = sigmoid(s[i,t]) * exp( sum_{j>=t} -softplus(s[i,j]) ),  s = QK^T/sqrt(D)
// Carry decays ~0.8/column => only top ~100-160 columns matter. Reverse-stream
// K-tiles with block-wide early exit when all 64 rows' carry < -40.
//
// v6: kill the serialized-load latency chain (v4/v5 were latency-bound:
// ~32 serial L3 round-trips per tile). Block = 4 waves sharing one head's
// K/V tiles staged in LDS (4x fewer L2/L3 reads); T14 reg-staging pipeline
// (issue next tile's 6 float4 loads before compute, ds_write after, one
// barrier per tile) -> ~1 memory latency per tile. ws holds K(hi/lo bf16)
// and V(f16) in fragment-major order so staging is a linear copy and all
// ds_read_b128 are lane-contiguous (conflict-free). Math identical to v4.

constexpr int B_ = 2, H_ = 16, S_ = 2048, D_ = 128;
constexpr int BK = 32, NTILES = S_ / BK;    // 64 tiles
constexpr int NJ = 256, NFT = NJ / BK;      // 8 precomputed "fast" tiles
constexpr int TILE_SH = 12288;              // shorts per ws tile: K 16KB + V 8KB
constexpr float SCALE = 0.08838834764831845f;   // 1/sqrt(128)
constexpr float EXIT_THR = -40.0f;

typedef __attribute__((ext_vector_type(8))) short bf16x8;
typedef __attribute__((ext_vector_type(8))) _Float16 f16x8;
typedef __attribute__((ext_vector_type(8))) unsigned short u16x8;
typedef __attribute__((ext_vector_type(4))) float f32x4;
typedef __attribute__((ext_vector_type(2))) __fp16 fp16v2;

static __device__ __forceinline__ unsigned short bf16rtn(float x) {
    unsigned int u = __float_as_uint(x);
    u += 0x7FFFu + ((u >> 16) & 1u);
    return (unsigned short)(u >> 16);
}

// sigmoid(x) and log_sigmoid(-x) = -softplus(x), f32 (mirrors reference)
static __device__ __forceinline__ void zlb(float x, float& z, float& lb) {
    float en = __expf(-fabsf(x));
    float rc = __fdividef(1.0f, 1.0f + en);
    z  = (x >= 0.0f) ? rc : en * rc;
    lb = -(fmaxf(x, 0.0f) + __logf(1.0f + en));
}

// ---------------- pre-kernel: fragment-major K(hi/lo) + V into ws ----------------
// ws tile region (per bh, tt): 24KB = [K: ck(4) x half(2) x part(2) x lane(64) x 8 shorts]
//                                     [V: ck(8) x lane(64) x 8 shorts] at +8192 shorts
__global__ __launch_bounds__(256)
void sb_pre(const float* __restrict__ kg, const float* __restrict__ vg,
            unsigned short* __restrict__ wsf) {
    __shared__ float Vs[32][132];
    const int tid = threadIdx.x;
    const int blk = blockIdx.x;
    if (blk < 256) {            // K: one block per (bh, tt)
        const int bh = blk >> 3, tt = blk & 7;
        unsigned short* dstT = wsf + (size_t)(bh * NFT + tt) * TILE_SH;
        const float* srcT = kg + ((size_t)bh * S_ + (S_ - NJ) + tt * 32) * D_;
        #pragma unroll
        for (int it = 0; it < 2; ++it) {
            int p = it * 256 + tid;            // 512 chunk-pairs
            int ck = (p >> 7) & 3, half = (p >> 6) & 1, ln = p & 63;
            int row = half * 16 + (ln & 15);
            int col = ck * 32 + (ln >> 4) * 8;
            const float* s = srcT + (size_t)row * D_ + col;
            u16x8 h8, l8;
            #pragma unroll
            for (int e = 0; e < 8; ++e) {
                float x = s[e];
                unsigned short hb = bf16rtn(x);
                float hf = __uint_as_float((unsigned int)hb << 16);
                h8[e] = hb;
                l8[e] = bf16rtn(x - hf);
            }
            *(u16x8*)(dstT + (((ck * 2 + half) * 2 + 0) * 64 + ln) * 8) = h8;
            *(u16x8*)(dstT + (((ck * 2 + half) * 2 + 1) * 64 + ln) * 8) = l8;
        }
    } else {                    // V: one block per (bh, tt)
        const int vb = blk - 256;
        const int bh = vb >> 3, tt = vb & 7;
        const float* src = vg + ((size_t)bh * S_ + (S_ - NJ) + tt * 32) * D_;
        #pragma unroll
        for (int it = 0; it < 4; ++it) {
            int idx = it * 256 + tid;
            int j = idx >> 5, d4 = idx & 31;
            *(float4*)&Vs[j][d4 * 4] = *(const float4*)(src + (size_t)j * D_ + d4 * 4);
        }
        __syncthreads();
        unsigned short* dstT = wsf + (size_t)(bh * NFT + tt) * TILE_SH + 8192;
        #pragma unroll
        for (int it = 0; it < 2; ++it) {
            int p = it * 256 + tid;            // 512 chunks
            int ck = p >> 6, ln = p & 63;
            int d = ck * 16 + (ln & 15);
            int j0 = (ln >> 4) * 8;
            f16x8 v;
            #pragma unroll
            for (int e = 0; e < 8; ++e) v[e] = (_Float16)Vs[j0 + e][d];
            *(f16x8*)(dstT + (ck * 64 + ln) * 8) = v;
        }
    }
}

// ---------------- scan + P pack + PV (verbatim v4 math) ----------------
static __device__ __forceinline__ float scan_pack_pv(
    f32x4 st0, f32x4 st1, int lane, int g, int m16,
    const f16x8* vf, f32x4* accO, unsigned int (*Pw)[20], float carry)
{
    float lbL[4], lbU[4], zL[4], zU[4];
    #pragma unroll
    for (int r = 0; r < 4; ++r) { zlb(st0[r], zL[r], lbL[r]); zlb(st1[r], zU[r], lbU[r]); }
    float sL3 = lbL[3], sL2 = lbL[2] + sL3, sL1 = lbL[1] + sL2, sL0 = lbL[0] + sL1;
    float sU3 = lbU[3], sU2 = lbU[2] + sU3, sU1 = lbU[1] + sU2, sU0 = lbU[0] + sU1;
    float sufL[4] = {sL0, sL1, sL2, sL3};
    float sufU[4] = {sU0, sU1, sU2, sU3};
    float TL = sL0, TU = sU0;
    float IU = TU, IL = TL;
    { float t1 = __shfl(IU, (lane + 16) & 63); if (g < 3) IU += t1;
      float t2 = __shfl(IU, (lane + 32) & 63); if (g < 2) IU += t2; }
    { float t1 = __shfl(IL, (lane + 16) & 63); if (g < 3) IL += t1;
      float t2 = __shfl(IL, (lane + 32) & 63); if (g < 2) IL += t2; }
    float TotU = __shfl(IU, m16);
    float EU = IU - TU, EL = IL - TL;
    float bU = carry + EU;
    float bL = carry + TotU + EL;
    float wU[4], wL[4];
    #pragma unroll
    for (int r = 0; r < 4; ++r) {
        wU[r] = zU[r] * __expf(bU + sufU[r]);
        wL[r] = zL[r] * __expf(bL + sufL[r]);
    }
    float TotL = __shfl(IL, m16);
    carry += TotU + TotL;

    union { fp16v2 h; unsigned int u; } cA, cB, cC, cD;
    cA.h = __builtin_amdgcn_cvt_pkrtz(wL[0], wL[1]);
    cB.h = __builtin_amdgcn_cvt_pkrtz(wL[2], wL[3]);
    cC.h = __builtin_amdgcn_cvt_pkrtz(wU[0], wU[1]);
    cD.h = __builtin_amdgcn_cvt_pkrtz(wU[2], wU[3]);
    *(uint2*)&Pw[m16][2 * g]     = make_uint2(cA.u, cB.u);
    *(uint2*)&Pw[m16][8 + 2 * g] = make_uint2(cC.u, cD.u);
    f16x8 pf = *(const f16x8*)&Pw[m16][4 * g];

    #pragma unroll
    for (int ck = 0; ck < 8; ++ck)
        accO[ck] = __builtin_amdgcn_mfma_f32_16x16x32_f16(pf, vf[ck], accO[ck], 0, 0, 0);
    return carry;
}

// ---------------- fast tile: everything from the staged LDS tile ----------------
static __device__ __forceinline__ float fast_tile_lds(
    const unsigned short* __restrict__ tile, int lane, int g, int m16,
    const bf16x8* qhi, const bf16x8* qlo,
    f32x4* accO, unsigned int (*Pw)[20], float carry)
{
    f16x8 vf[8];
    #pragma unroll
    for (int ck = 0; ck < 8; ++ck)
        vf[ck] = *(const f16x8*)(tile + 8192 + ck * 512 + lane * 8);

    f32x4 st0 = {0.f, 0.f, 0.f, 0.f}, st1 = {0.f, 0.f, 0.f, 0.f};
    #pragma unroll
    for (int ck = 0; ck < 4; ++ck) {
        bf16x8 kh0 = *(const bf16x8*)(tile + (((ck * 2 + 0) * 2 + 0) * 64 + lane) * 8);
        bf16x8 kl0 = *(const bf16x8*)(tile + (((ck * 2 + 0) * 2 + 1) * 64 + lane) * 8);
        bf16x8 kh1 = *(const bf16x8*)(tile + (((ck * 2 + 1) * 2 + 0) * 64 + lane) * 8);
        bf16x8 kl1 = *(const bf16x8*)(tile + (((ck * 2 + 1) * 2 + 1) * 64 + lane) * 8);
        st0 = __builtin_amdgcn_mfma_f32_16x16x32_bf16(kh0, qhi[ck], st0, 0, 0, 0);
        st0 = __builtin_amdgcn_mfma_f32_16x16x32_bf16(kl0, qhi[ck], st0, 0, 0, 0);
        st0 = __builtin_amdgcn_mfma_f32_16x16x32_bf16(kh0, qlo[ck], st0, 0, 0, 0);
        st1 = __builtin_amdgcn_mfma_f32_16x16x32_bf16(kh1, qhi[ck], st1, 0, 0, 0);
        st1 = __builtin_amdgcn_mfma_f32_16x16x32_bf16(kl1, qhi[ck], st1, 0, 0, 0);
        st1 = __builtin_amdgcn_mfma_f32_16x16x32_bf16(kh1, qlo[ck], st1, 0, 0, 0);
    }
    return scan_pack_pv(st0, st1, lane, g, m16, vf, accO, Pw, carry);
}

// ---------------- slow tile (cold; statistically never runs) ----------------
static __device__ __forceinline__ float slow_tile(
    int t, int lane, int g, int m16,
    const float* kb_p, const float* vb_p,
    const bf16x8* qhi, const bf16x8* qlo,
    f32x4* accO, unsigned int (*Pw)[20], float carry)
{
    const int j0 = t * BK;
    const float* kr0 = kb_p + (size_t)(j0 + m16) * D_;
    const float* kr1 = kr0 + (size_t)16 * D_;
    f32x4 st0 = {0.f, 0.f, 0.f, 0.f}, st1 = {0.f, 0.f, 0.f, 0.f};
    #pragma unroll
    for (int ck = 0; ck < 4; ++ck) {
        bf16x8 kh0, kl0, kh1, kl1;
        #pragma unroll
        for (int e = 0; e < 8; ++e) {
            float x0 = kr0[ck * 32 + g * 8 + e];
            unsigned short h0 = bf16rtn(x0);
            kh0[e] = (short)h0;
            kl0[e] = (short)bf16rtn(x0 - __uint_as_float((unsigned int)h0 << 16));
            float x1 = kr1[ck * 32 + g * 8 + e];
            unsigned short h1 = bf16rtn(x1);
            kh1[e] = (short)h1;
            kl1[e] = (short)bf16rtn(x1 - __uint_as_float((unsigned int)h1 << 16));
        }
        st0 = __builtin_amdgcn_mfma_f32_16x16x32_bf16(kh0, qhi[ck], st0, 0, 0, 0);
        st0 = __builtin_amdgcn_mfma_f32_16x16x32_bf16(kl0, qhi[ck], st0, 0, 0, 0);
        st0 = __builtin_amdgcn_mfma_f32_16x16x32_bf16(kh0, qlo[ck], st0, 0, 0, 0);
        st1 = __builtin_amdgcn_mfma_f32_16x16x32_bf16(kh1, qhi[ck], st1, 0, 0, 0);
        st1 = __builtin_amdgcn_mfma_f32_16x16x32_bf16(kl1, qhi[ck], st1, 0, 0, 0);
        st1 = __builtin_amdgcn_mfma_f32_16x16x32_bf16(kh1, qlo[ck], st1, 0, 0, 0);
    }
    f16x8 vf[8];
    #pragma unroll
    for (int ck = 0; ck < 8; ++ck) {
        #pragma unroll
        for (int e = 0; e < 8; ++e)
            vf[ck][e] = (_Float16)vb_p[(size_t)(j0 + g * 8 + e) * D_ + ck * 16 + m16];
    }
    return scan_pack_pv(st0, st1, lane, g, m16, vf, accO, Pw, carry);
}

// ---------------- main kernel: 4 waves (64 rows, same head) per block ----------------
template<int NFAST>
__global__ __launch_bounds__(256, 2)
void sb_attn(const float* __restrict__ qg, const float* __restrict__ kg,
             const float* __restrict__ vg, float* __restrict__ outg,
             const unsigned short* __restrict__ wsf) {
    __shared__ __align__(16) unsigned short Tiles[2][TILE_SH];   // 48KB dbuf
    __shared__ unsigned int PwAll[4][16][20];
    __shared__ int flags[2][4];

    const int tid = threadIdx.x;
    const int w = tid >> 6, lane = tid & 63;
    const int g = lane >> 4, m16 = lane & 15;

    // XCD-chunked swizzle: 1024 blocks = 8 XCDs x 128; same-head blocks co-XCD
    const int bid = blockIdx.x;
    const int wg  = ((bid & 7) << 7) | (bid >> 3);
    const int bh  = wg >> 5;           // 32 blocks of 64 rows per head
    const int qb  = wg & 31;

    const float* qb_p = qg + ((size_t)bh * S_ + qb * 64 + w * 16) * D_;
    const float* kb_p = kg + (size_t)bh * S_ * D_;
    const float* vb_p = vg + (size_t)bh * S_ * D_;
    float*       ob_p = outg + ((size_t)bh * S_ + qb * 64 + w * 16) * D_;
    unsigned int (*Pw)[20] = PwAll[w];

    constexpr int TMIN = NTILES - NFAST;
    const unsigned short* wsb = wsf + (size_t)bh * NFT * TILE_SH;

    // prologue: issue stage loads for tile 63 (region NFT-1)
    float4 stg[6];
    if constexpr (NFAST > 0) {
        const float4* src = (const float4*)(wsb + (size_t)(NFT - 1) * TILE_SH);
        #pragma unroll
        for (int i = 0; i < 6; ++i) stg[i] = src[i * 256 + tid];
    }

    // Q frags (persistent, bf16 hi/lo): lane holds Q[m16][ck*32+g*8+e]*SCALE
    bf16x8 qhi[4], qlo[4];
    #pragma unroll
    for (int ck = 0; ck < 4; ++ck) {
        const float* p = qb_p + (size_t)m16 * D_ + ck * 32 + g * 8;
        #pragma unroll
        for (int e = 0; e < 8; ++e) {
            float x = p[e] * SCALE;
            unsigned short hb = bf16rtn(x);
            float hf = __uint_as_float((unsigned int)hb << 16);
            qhi[ck][e] = (short)hb;
            qlo[ck][e] = (short)bf16rtn(x - hf);
        }
    }

    f32x4 accO[8];
    #pragma unroll
    for (int ck = 0; ck < 8; ++ck) accO[ck] = (f32x4){0.f, 0.f, 0.f, 0.f};

    float carry = 0.f;
    bool anyalive = true;
    int t = NTILES - 1, cur = 0;

    if constexpr (NFAST > 0) {
        // write prologue tile, publish
        #pragma unroll
        for (int i = 0; i < 6; ++i)
            *(float4*)(Tiles[0] + (size_t)(i * 256 + tid) * 8) = stg[i];
        __syncthreads();

        while (true) {
            const bool havenext = (t - 1 >= TMIN);
            if (havenext) {   // issue next tile's loads before compute (T14)
                const float4* src = (const float4*)(wsb + (size_t)(t - 1 - TMIN) * TILE_SH);
                #pragma unroll
                for (int i = 0; i < 6; ++i) stg[i] = src[i * 256 + tid];
            }
            carry = fast_tile_lds(Tiles[cur], lane, g, m16, qhi, qlo, accO, Pw, carry);
            int walive = (__ballot(carry > EXIT_THR) != 0ULL) ? 1 : 0;
            const int par = t & 1;
            if (lane == 0) flags[par][w] = walive;
            if (havenext) {   // write-late: loads have drained under compute
                unsigned short* dn = Tiles[cur ^ 1];
                #pragma unroll
                for (int i = 0; i < 6; ++i)
                    *(float4*)(dn + (size_t)(i * 256 + tid) * 8) = stg[i];
            }
            __syncthreads();
            anyalive = (flags[par][0] | flags[par][1] | flags[par][2] | flags[par][3]) != 0;
            --t; cur ^= 1;
            if (!anyalive || t < TMIN) break;
        }
    }

    if (anyalive) {   // per-wave slow path (barrier-free)
        bool wave_alive = (__ballot(carry > EXIT_THR) != 0ULL);
        for (; t >= 0 && wave_alive; --t) {
            carry = slow_tile(t, lane, g, m16, kb_p, vb_p, qhi, qlo, accO, Pw, carry);
            wave_alive = (__ballot(carry > EXIT_THR) != 0ULL);
        }
    }

    // write O[4g+r][ck*16+m16]
    #pragma unroll
    for (int ck = 0; ck < 8; ++ck) {
        #pragma unroll
        for (int r = 0; r < 4; ++r) {
            ob_p[(size_t)(g * 4 + r) * D_ + ck * 16 + m16] = accO[ck][r];
        }
    }
}

extern "C" void kernel_launch(void* const* d_in, const int* in_sizes, int n_in,
                              void* d_out, int out_size, void* d_ws, size_t ws_size,
                              hipStream_t stream) {
    (void)in_sizes; (void)n_in; (void)out_size;
    const float* q = (const float*)d_in[0];
    const float* k = (const float*)d_in[1];
    const float* v = (const float*)d_in[2];
    float* out = (float*)d_out;

    const size_t need = (size_t)B_ * H_ * NFT * TILE_SH * 2;   // 6 MiB
    unsigned short* wsf = (unsigned short*)d_ws;

    dim3 grid(B_ * H_ * (S_ / 64));   // 1024 blocks x 256 threads

    if (ws_size >= need) {
        sb_pre<<<512, 256, 0, stream>>>(k, v, wsf);
        sb_attn<NFT><<<grid, 256, 0, stream>>>(q, k, v, out, wsf);
    } else {
        sb_attn<0><<<grid, 256, 0, stream>>>(q, k, v, out, wsf);
    }
}